// Round 4
// baseline (194.134 us; speedup 1.0000x reference)
//
#include <hip/hip_runtime.h>

#define OUT 7
#define NCH 256
#define NROI 512
#define NS 14            // bilinear samples per axis (7 bins x 2)
#define CCH 16           // channels per block
#define PLANE 901        // u32 words per ch-pair plane (odd; > max Ht*Wd = 885)
#define TPR (NCH * OUT * OUT)

__device__ __forceinline__ float rfl_f(float v) {
    return __int_as_float(__builtin_amdgcn_readfirstlane(__float_as_int(v)));
}

// D[15:0]=bf16(lo), D[31:16]=bf16(hi), RNE — matches the original manual round.
__device__ __forceinline__ unsigned int cvt_pk_bf16(float lo, float hi) {
    unsigned int r;
    asm("v_cvt_pk_bf16_f32 %0, %1, %2" : "=v"(r) : "v"(lo), "v"(hi));
    return r;
}

// One 1-D bilinear tap: sample sidx of 14, legacy aligned=False semantics.
__device__ __forceinline__ void tap1d(float start, float bin, int sidx, int H,
                                      int& lo, int& hi, float& fr, float& vv) {
    int p = sidx >> 1, half = sidx & 1;
    float c = start + ((float)p + (half ? 0.75f : 0.25f)) * bin;
    vv = (c >= -1.0f && c <= (float)H) ? 0.5f : 0.0f;   // vy*vx = 0.25
    c = fmaxf(c, 0.0f);
    int l = (int)c;
    if (l >= H - 1) { lo = H - 1; hi = H - 1; fr = 0.0f; }
    else            { lo = l;     hi = l + 1; fr = c - (float)l; }
}

// Block = (RoI, 16-channel chunk).
// Phase 1: uniform footprint extents + per-sample weight/rel-index LUT.
// Phase 2: stage the FULL rectangular footprint (Ht x Wd x 16ch, bf16-packed)
//   into LDS with row-contiguous coalesced loads. Each wave owns 4 channels
//   (2 ch-pair planes) and walks rows via a hand-rolled 4-deep software
//   pipeline (named regs, scalar row addressing) -> 16 loads in flight.
//   Every feature cache line is fetched exactly once (the old tap-gather
//   fetched each ~4x as divergent gathers).
// Phase 3: bilinear pool 49 px x 8 ch-pairs straight from the LDS footprint.
// Phase 4: repack via LDS, float4 store.
// LDS word: cp*PLANE + row*Wd + col  (cp = channel pair 0..7; PLANE odd).
__global__ __launch_bounds__(256, 4) void roi_align_fp_kernel(
        const float* __restrict__ f0, const float* __restrict__ f1,
        const float* __restrict__ f2, const float* __restrict__ f3,
        const float* __restrict__ boxes, float* __restrict__ out) {
    __shared__ __align__(16) unsigned int sm32[8 * PLANE];   // 28,832 B
    __shared__ float lyS[NS], vyS[NS], lxS[NS], vxS[NS];
    __shared__ int rowLrel[NS], rowHrel[NS], colLrel[NS], colHrel[NS];

    int g    = blockIdx.x;
    int xcd  = g & 7;
    int slot = g >> 3;
    int rr_  = slot >> 4;
    int q    = slot & 15;          // 16-channel chunk
    int r    = rr_ * 8 + xcd;      // RoI id: all 16 chunks share g%8 (same XCD)
    int tid  = (int)threadIdx.x;

    // ---------------- wave-uniform RoI meta ----------------
    float bx1 = rfl_f(boxes[r * 4 + 0]);
    float by1 = rfl_f(boxes[r * 4 + 1]);
    float bx2 = rfl_f(boxes[r * 4 + 2]);
    float by2 = rfl_f(boxes[r * 4 + 3]);

    float area = (bx2 - bx1) * (by2 - by1);
    float s    = sqrtf(area);
    float lvl  = floorf(4.0f + log2f(s * (1.0f / 224.0f) + 1e-6f));
    lvl        = fminf(fmaxf(lvl, 2.0f), 5.0f);
    int level  = __builtin_amdgcn_readfirstlane((int)lvl - 2);

    const float* f; int H; float scale;
    switch (level) {
        case 0:  f = f0; H = 200; scale = 0.25f;    break;
        case 1:  f = f1; H = 100; scale = 0.125f;   break;
        case 2:  f = f2; H = 50;  scale = 0.0625f;  break;
        default: f = f3; H = 25;  scale = 0.03125f; break;
    }

    float x1 = bx1 * scale, y1 = by1 * scale;
    float roi_w = fmaxf(bx2 * scale - x1, 1.0f);
    float roi_h = fmaxf(by2 * scale - y1, 1.0f);
    float bin_w = roi_w * (1.0f / OUT);
    float bin_h = roi_h * (1.0f / OUT);

    // ---------------- phase 1a: uniform footprint extents ----------------
    // Tap coords are monotone in sample idx -> extremes at samples 0 and 13.
    int lo0, hi0, lo13, hi13; float frT, vvT;
    tap1d(y1, bin_h, 0,  H, lo0, hi0, frT, vvT);
    tap1d(y1, bin_h, 13, H, lo13, hi13, frT, vvT);
    int rowMin = __builtin_amdgcn_readfirstlane(lo0);
    int rowMax = __builtin_amdgcn_readfirstlane(hi13);
    tap1d(x1, bin_w, 0,  H, lo0, hi0, frT, vvT);
    tap1d(x1, bin_w, 13, H, lo13, hi13, frT, vvT);
    int colMin = __builtin_amdgcn_readfirstlane(lo0);
    int colMax = __builtin_amdgcn_readfirstlane(hi13);
    int Ht = rowMax - rowMin + 1;     // <= ~100
    int Wd = colMax - colMin + 1;     // <= ~98 ; Ht*Wd <= 885 < PLANE

    // ---------------- phase 1b: weight + relative-index LUT ----------------
    if (tid < NS) {                       // y samples
        int lo, hi; float fr, vv;
        tap1d(y1, bin_h, tid, H, lo, hi, fr, vv);
        lyS[tid] = fr; vyS[tid] = vv;
        rowLrel[tid] = lo - rowMin; rowHrel[tid] = hi - rowMin;
    } else if (tid >= 32 && tid < 32 + NS) {   // x samples
        int t = tid - 32;
        int lo, hi; float fr, vv;
        tap1d(x1, bin_w, t, H, lo, hi, fr, vv);
        lxS[t] = fr; vxS[t] = vv;
        colLrel[t] = lo - colMin; colHrel[t] = hi - colMin;
    }

    // ---------------- phase 2: stage footprint, 4-deep pipelined ----------
    int bidx = r >> 8;   // 256 RoIs per batch image
    size_t HH = (size_t)(H * H);
    int lane = tid & 63;
    int wv   = __builtin_amdgcn_readfirstlane(tid >> 6);   // wave 0..3 (scalar)

    // wave wv covers channels 4wv..4wv+3 = ch-pairs 2wv, 2wv+1
    const float* pw0 = f + ((size_t)(bidx * NCH + q * CCH + 4 * wv)) * HH
                         + (size_t)(rowMin * H + colMin);
    size_t HH1 = HH, HH2 = 2 * HH, HH3 = 3 * HH;
    int wb0 = (2 * wv) * PLANE;
    int wb1 = wb0 + PLANE;

    bool TWO = (Wd > 64);
    int  cA  = (lane < Wd) ? lane : (Wd - 1);        // clamp: dup last elem
    int  cB  = TWO ? ((lane + 64 < Wd) ? lane + 64 : Wd - 1) : 0;
    bool wA  = (lane < Wd);
    bool wB  = TWO && (lane + 64 < Wd);

#define DECLS(s) float A##s, B##s, C##s, D##s, E##s = 0, F##s = 0, G##s = 0, I##s = 0;
    DECLS(0) DECLS(1) DECLS(2) DECLS(3)

#define STG_ISSUE(s, rv) { \
        int rr = (rv) < Ht ? (rv) : (Ht - 1); \
        const float* p = pw0 + (size_t)(rr * H); \
        A##s = p[cA]; B##s = p[HH1 + cA]; C##s = p[HH2 + cA]; D##s = p[HH3 + cA]; \
        if (TWO) { E##s = p[cB]; F##s = p[HH1 + cB]; G##s = p[HH2 + cB]; I##s = p[HH3 + cB]; } }

#define STG_CONSUME(s, rv) { \
        if ((rv) < Ht) { \
            int wb = (rv) * Wd + lane; \
            if (wA) { \
                sm32[wb0 + wb] = cvt_pk_bf16(A##s, B##s); \
                sm32[wb1 + wb] = cvt_pk_bf16(C##s, D##s); } \
            if (wB) { \
                sm32[wb0 + wb + 64] = cvt_pk_bf16(E##s, F##s); \
                sm32[wb1 + wb + 64] = cvt_pk_bf16(G##s, I##s); } } }

    STG_ISSUE(0, 0) STG_ISSUE(1, 1) STG_ISSUE(2, 2) STG_ISSUE(3, 3)
    for (int rw = 0; rw < Ht; rw += 4) {
        STG_CONSUME(0, rw)     STG_ISSUE(0, rw + 4)
        STG_CONSUME(1, rw + 1) STG_ISSUE(1, rw + 5)
        STG_CONSUME(2, rw + 2) STG_ISSUE(2, rw + 6)
        STG_CONSUME(3, rw + 3) STG_ISSUE(3, rw + 7)
    }
    __syncthreads();

    // ---------------- phase 3: pool 49 px x 8 channel-pairs ----------------
    float accx[2], accy[2];
#pragma unroll
    for (int i = 0; i < 2; ++i) { accx[i] = 0.0f; accy[i] = 0.0f; }

#pragma unroll
    for (int i = 0; i < 2; ++i) {
        int o = tid + 256 * i;
        if (o < 392) {
            int cp = o & 7, px = o >> 3;
            int ph = px / 7, pw = px - ph * 7;
            int cpP = cp * PLANE;
            float ax = 0.0f, ay = 0.0f;
#pragma unroll
            for (int iy = 0; iy < 2; ++iy) {
                int sy = ph * 2 + iy;
                float ly = lyS[sy], hy = 1.0f - ly;
                float vy = vyS[sy];
                int rL = cpP + rowLrel[sy] * Wd;
                int rH = cpP + rowHrel[sy] * Wd;
#pragma unroll
                for (int ix = 0; ix < 2; ++ix) {
                    int sx = pw * 2 + ix;
                    float lx = lxS[sx], hx = 1.0f - lx;
                    float m  = vy * vxS[sx];       // 0.25 if valid else 0
                    int cL = colLrel[sx], cH = colHrel[sx];
                    unsigned int u00 = sm32[rL + cL];
                    unsigned int u01 = sm32[rL + cH];
                    unsigned int u10 = sm32[rH + cL];
                    unsigned int u11 = sm32[rH + cH];
                    float w00 = hy * hx * m, w01 = hy * lx * m;
                    float w10 = ly * hx * m, w11 = ly * lx * m;
                    ax = fmaf(w00, __uint_as_float(u00 << 16), ax);
                    ay = fmaf(w00, __uint_as_float(u00 & 0xFFFF0000u), ay);
                    ax = fmaf(w01, __uint_as_float(u01 << 16), ax);
                    ay = fmaf(w01, __uint_as_float(u01 & 0xFFFF0000u), ay);
                    ax = fmaf(w10, __uint_as_float(u10 << 16), ax);
                    ay = fmaf(w10, __uint_as_float(u10 & 0xFFFF0000u), ay);
                    ax = fmaf(w11, __uint_as_float(u11 << 16), ax);
                    ay = fmaf(w11, __uint_as_float(u11 & 0xFFFF0000u), ay);
                }
            }
            accx[i] = ax; accy[i] = ay;
        }
    }
    __syncthreads();   // LDS reads done; reuse sm32 for output repack

    // ---------------- phase 4: repack via LDS, contiguous float4 store -----
    float* smf = (float*)sm32;
#pragma unroll
    for (int i = 0; i < 2; ++i) {
        int o = tid + 256 * i;
        if (o < 392) {
            int cp = o & 7, px = o >> 3;
            smf[(cp * 2 + 0) * 49 + px] = accx[i];  // even channel (low ushort)
            smf[(cp * 2 + 1) * 49 + px] = accy[i];  // odd channel (high ushort)
        }
    }
    __syncthreads();

    float* dst = out + (size_t)r * TPR + (size_t)q * (CCH * 49);
    if (tid < 196)
        ((float4*)dst)[tid] = ((const float4*)smf)[tid];
}

extern "C" void kernel_launch(void* const* d_in, const int* in_sizes, int n_in,
                              void* d_out, int out_size, void* d_ws, size_t ws_size,
                              hipStream_t stream) {
    const float* f0    = (const float*)d_in[0];
    const float* f1    = (const float*)d_in[1];
    const float* f2    = (const float*)d_in[2];
    const float* f3    = (const float*)d_in[3];
    const float* boxes = (const float*)d_in[4];
    float* out         = (float*)d_out;

    roi_align_fp_kernel<<<NROI * 16, 256, 0, stream>>>(f0, f1, f2, f3, boxes, out);
}

// Round 5
// 178.935 us; speedup vs baseline: 1.0849x; 1.0849x over previous
//
#include <hip/hip_runtime.h>

#define OUT 7
#define NCH 256
#define NROI 512
#define NS 14            // bilinear samples per axis (7 bins x 2)
#define NT 28            // tap slots per axis (lo/hi per sample)
#define CCH 16           // channels per block
#define W9 9             // LDS words per row-slot within a col-slot: 8 cp + 1 pad
#define WPC 253          // LDS words per col-slot: 28*9 + 1 (odd -> conflict-free)
#define TPR (NCH * OUT * OUT)

__device__ __forceinline__ float rfl_f(float v) {
    return __int_as_float(__builtin_amdgcn_readfirstlane(__float_as_int(v)));
}

// 8B load with only 4B alignment guarantee (col pair may start at odd col).
__device__ __forceinline__ float2 ld2(const float* p) {
    float2 r;
    __builtin_memcpy(&r, p, sizeof(float2));
    return r;
}

// D[15:0]=bf16(lo), D[31:16]=bf16(hi), RNE — matches the original manual round.
__device__ __forceinline__ unsigned int cvt_pk_bf16(float lo, float hi) {
    unsigned int r;
    asm("v_cvt_pk_bf16_f32 %0, %1, %2" : "=v"(r) : "v"(lo), "v"(hi));
    return r;
}

// Block = (RoI, 16-channel chunk). Tap-gather structure (R3) with the
// occupancy lie fixed: amdgpu_waves_per_eu(4,4) tells the RA to budget
// 128 VGPRs (LDS caps us at ~5 blocks/CU anyway; default policy was
// scheduling for 10+ waves/SIMD at 44 VGPRs, serializing all loads).
// Loads issue FIRST (per-lane addresses from the wave-uniform box), pinned
// above the convert region by an IR-level memory fence + sched_barrier ->
// all 28 col-pair loads in flight per lane. Weight LUT overlaps the loads.
// Phase 3: 49 px x 8 channel-pairs pooled from LDS. Phase 4: float4 store.
// LDS word index: colslot*253 + rowslot*9 + cp  (cp = channel pair 0..7).
__global__ void
__attribute__((amdgpu_flat_work_group_size(256, 256), amdgpu_waves_per_eu(4, 4)))
roi_align_tap16_kernel(
        const float* __restrict__ f0, const float* __restrict__ f1,
        const float* __restrict__ f2, const float* __restrict__ f3,
        const float* __restrict__ boxes, float* __restrict__ out) {
    __shared__ __align__(16) unsigned short sm[NT * WPC * 2];  // 28,336 B
    __shared__ float lyS[NS], vyS[NS], lxS[NS], vxS[NS];

    int g    = blockIdx.x;
    int xcd  = g & 7;
    int slot = g >> 3;
    int rr   = slot >> 4;
    int q    = slot & 15;          // 16-channel chunk
    int r    = rr * 8 + xcd;       // RoI id: all 16 chunks share g%8 (same XCD)
    int tid  = (int)threadIdx.x;

    // ---------------- wave-uniform RoI meta ----------------
    float bx1 = rfl_f(boxes[r * 4 + 0]);
    float by1 = rfl_f(boxes[r * 4 + 1]);
    float bx2 = rfl_f(boxes[r * 4 + 2]);
    float by2 = rfl_f(boxes[r * 4 + 3]);

    float area = (bx2 - bx1) * (by2 - by1);
    float s    = sqrtf(area);
    float lvl  = floorf(4.0f + log2f(s * (1.0f / 224.0f) + 1e-6f));
    lvl        = fminf(fmaxf(lvl, 2.0f), 5.0f);
    int level  = __builtin_amdgcn_readfirstlane((int)lvl - 2);

    const float* f; int H; float scale;
    switch (level) {
        case 0:  f = f0; H = 200; scale = 0.25f;    break;
        case 1:  f = f1; H = 100; scale = 0.125f;   break;
        case 2:  f = f2; H = 50;  scale = 0.0625f;  break;
        default: f = f3; H = 25;  scale = 0.03125f; break;
    }
    float Hf = (float)H;

    float x1 = bx1 * scale, y1 = by1 * scale;
    float roi_w = fmaxf(bx2 * scale - x1, 1.0f);
    float roi_h = fmaxf(by2 * scale - y1, 1.0f);
    float bin_w = roi_w * (1.0f / OUT);
    float bin_h = roi_h * (1.0f / OUT);

    // ---------------- phase 2a: per-lane tap addresses + ISSUE all loads ----
    int bidx = r >> 8;   // 256 RoIs per batch image
    size_t HH = (size_t)(H * H);
    const float* plane = f + (size_t)(bidx * NCH + q * CCH) * HH;

    int lane = tid & 63;
    int wave = tid >> 6;
    int cq   = lane / 14;  if (cq > 3) cq = 3;         // channel quad 0..3
    int sp   = lane - cq * 14;  if (sp > 13) sp = 13;  // x sample 0..13
    bool act = lane < 56;

    // col pair for this lane's x sample (bitwise-identical to weight-LUT math)
    int pw = sp >> 1, ixs = sp & 1;
    float xs = x1 + ((float)pw + (ixs ? 0.75f : 0.25f)) * bin_w;
    xs = fmaxf(xs, 0.0f);
    int xl = (int)xs;
    int c0; bool sel;
    if (xl >= H - 1) { c0 = H - 2; sel = true; }   // clamped: both taps = f[H-1]
    else             { c0 = xl;    sel = false; }

    // rows for this wave's 7 row-slots (slot rs -> y sample rs>>1, lo/hi rs&1)
    int roff[7];
#pragma unroll
    for (int t = 0; t < 7; ++t) {
        int rs = wave * 7 + t;
        int sy = rs >> 1;
        int ph = sy >> 1, iy = sy & 1;
        float ys = y1 + ((float)ph + (iy ? 0.75f : 0.25f)) * bin_h;
        ys = fmaxf(ys, 0.0f);
        int yl = (int)ys;
        int row = (yl >= H - 1) ? (H - 1) : (yl + (rs & 1));
        roff[t] = row * H + c0;
    }

    const float* base = plane + (size_t)(cq * 4) * HH;   // ch 4cq..4cq+3

    // issue ALL 28 col-pair loads, then an IR-level memory fence: loads
    // cannot sink past an asm memory clobber -> true 28-deep batch.
    float2 v[7][4];
#pragma unroll
    for (int t = 0; t < 7; ++t)
#pragma unroll
        for (int cc = 0; cc < 4; ++cc)
            v[t][cc] = ld2(base + (size_t)cc * HH + (size_t)roff[t]);
    asm volatile("" ::: "memory");
    __builtin_amdgcn_sched_barrier(0);

    // ---------------- phase 1 (overlapped): weight LUT ----------------
    if (tid < NS) {                       // y samples
        int ph = tid >> 1, iy = tid & 1;
        float y = y1 + ((float)ph + (iy ? 0.75f : 0.25f)) * bin_h;
        float vv = (y >= -1.0f && y <= Hf) ? 0.5f : 0.0f;   // vy*vx = 0.25
        y = fmaxf(y, 0.0f);
        int yl = (int)y;
        float ly = (yl >= H - 1) ? 0.0f : (y - (float)yl);
        lyS[tid] = ly; vyS[tid] = vv;
    } else if (tid >= 32 && tid < 32 + NS) {   // x samples
        int t = tid - 32;
        int pw2 = t >> 1, ix2 = t & 1;
        float x = x1 + ((float)pw2 + (ix2 ? 0.75f : 0.25f)) * bin_w;
        float vv = (x >= -1.0f && x <= Hf) ? 0.5f : 0.0f;
        x = fmaxf(x, 0.0f);
        int xl2 = (int)x;
        float lx = (xl2 >= H - 1) ? 0.0f : (x - (float)xl2);
        lxS[t] = lx; vxS[t] = vv;
    }

    // ---------------- phase 2b: convert + stage into LDS ----------------
    unsigned int* smw_w = (unsigned int*)sm;
    int wbase = (2 * sp) * WPC + 2 * cq;
#pragma unroll
    for (int t = 0; t < 7; ++t) {
        int rs = wave * 7 + t;                     // row slot 0..27
        // lo tap value: clamped cols read (H-2,H-1) and both taps = f[H-1]
        float l0 = sel ? v[t][0].y : v[t][0].x;
        float l1 = sel ? v[t][1].y : v[t][1].x;
        float l2 = sel ? v[t][2].y : v[t][2].x;
        float l3 = sel ? v[t][3].y : v[t][3].x;
        unsigned int lo01 = cvt_pk_bf16(l0, l1);
        unsigned int lo23 = cvt_pk_bf16(l2, l3);
        unsigned int hi01 = cvt_pk_bf16(v[t][0].y, v[t][1].y);
        unsigned int hi23 = cvt_pk_bf16(v[t][2].y, v[t][3].y);
        if (act) {
            unsigned int* d0 = smw_w + wbase + rs * W9;
            d0[0]       = lo01;   // colslot 2sp,   cp 2cq
            d0[1]       = lo23;   // colslot 2sp,   cp 2cq+1
            d0[WPC]     = hi01;   // colslot 2sp+1, cp 2cq
            d0[WPC + 1] = hi23;   // colslot 2sp+1, cp 2cq+1
        }
    }
    __syncthreads();

    // ---------------- phase 3: pool 49 px x 8 channel-pairs ----------------
    const unsigned int* smw = (const unsigned int*)sm;
    float accx[2], accy[2];
#pragma unroll
    for (int i = 0; i < 2; ++i) { accx[i] = 0.0f; accy[i] = 0.0f; }

#pragma unroll
    for (int i = 0; i < 2; ++i) {
        int o = tid + 256 * i;
        if (o < 392) {
            int cp = o & 7, px = o >> 3;
            int ph = px / 7, pw2 = px - ph * 7;
            float ax = 0.0f, ay = 0.0f;
#pragma unroll
            for (int iy = 0; iy < 2; ++iy) {
                int sy = ph * 2 + iy;
                float ly = lyS[sy], hy = 1.0f - ly;
                float vy = vyS[sy];
                int r0 = (2 * sy) * W9 + cp;
                int r1 = r0 + W9;
#pragma unroll
                for (int ix = 0; ix < 2; ++ix) {
                    int sx = pw2 * 2 + ix;
                    float lx = lxS[sx], hx = 1.0f - lx;
                    float m  = vy * vxS[sx];       // 0.25 if valid else 0
                    int c0i = (2 * sx) * WPC;
                    int c1i = c0i + WPC;
                    unsigned int u00 = smw[c0i + r0];
                    unsigned int u01 = smw[c1i + r0];
                    unsigned int u10 = smw[c0i + r1];
                    unsigned int u11 = smw[c1i + r1];
                    float w00 = hy * hx * m, w01 = hy * lx * m;
                    float w10 = ly * hx * m, w11 = ly * lx * m;
                    ax = fmaf(w00, __uint_as_float(u00 << 16), ax);
                    ay = fmaf(w00, __uint_as_float(u00 & 0xFFFF0000u), ay);
                    ax = fmaf(w01, __uint_as_float(u01 << 16), ax);
                    ay = fmaf(w01, __uint_as_float(u01 & 0xFFFF0000u), ay);
                    ax = fmaf(w10, __uint_as_float(u10 << 16), ax);
                    ay = fmaf(w10, __uint_as_float(u10 & 0xFFFF0000u), ay);
                    ax = fmaf(w11, __uint_as_float(u11 << 16), ax);
                    ay = fmaf(w11, __uint_as_float(u11 & 0xFFFF0000u), ay);
                }
            }
            accx[i] = ax; accy[i] = ay;
        }
    }
    __syncthreads();   // LDS reads done; reuse sm for output repack

    // ---------------- phase 4: repack via LDS, contiguous float4 store ----------------
    float* smf = (float*)sm;
#pragma unroll
    for (int i = 0; i < 2; ++i) {
        int o = tid + 256 * i;
        if (o < 392) {
            int cp = o & 7, px = o >> 3;
            smf[(cp * 2 + 0) * 49 + px] = accx[i];  // even channel (low ushort)
            smf[(cp * 2 + 1) * 49 + px] = accy[i];  // odd channel (high ushort)
        }
    }
    __syncthreads();

    float* dst = out + (size_t)r * TPR + (size_t)q * (CCH * 49);
    if (tid < 196)
        ((float4*)dst)[tid] = ((const float4*)smf)[tid];
}

extern "C" void kernel_launch(void* const* d_in, const int* in_sizes, int n_in,
                              void* d_out, int out_size, void* d_ws, size_t ws_size,
                              hipStream_t stream) {
    const float* f0    = (const float*)d_in[0];
    const float* f1    = (const float*)d_in[1];
    const float* f2    = (const float*)d_in[2];
    const float* f3    = (const float*)d_in[3];
    const float* boxes = (const float*)d_in[4];
    float* out         = (float*)d_out;

    roi_align_tap16_kernel<<<NROI * 16, 256, 0, stream>>>(f0, f1, f2, f3, boxes, out);
}